// Round 4
// baseline (288.432 us; speedup 1.0000x reference)
//
#include <hip/hip_runtime.h>

// LatentTexture: quantize-STE (8b hi / 4b lo) + align_corners bilinear sample.
// Two-pass through d_ws:
//   pass 1 (= R8, byte-identical): streaming quantize + channel-last u8
//           repack, 1 px/thread scalar NT loads (256B/wave coalesced),
//           12B/px hiT records; 16B->12B bridged by store-side LDS repack
//           (lds[3t+r], stride 3 coprime 32 banks; threads 0..191 store the
//           block's 3072B contiguously, 16B/lane dense).
//   pass 2: 4 lanes/sample, lane l = (x-tap l&1, y-tap l>>1). Each lane
//           loads ONE 12B hi texel (dwordx3) + one lo dword, scales by its
//           corner weight, 2-step __shfl_xor butterfly sums the 4 corners,
//           lane l stores ch[4l..4l+4) as one fx4 -> wave stores 1KB dense.
//           2048 blocks = 32 waves/CU (vs R8's 16): 2x latency hiding for
//           the scattered texel gather.
// History: R1 direct 311; R2 4px-repack 308.6; R4 1px+NT+uint4 292.4/290.2;
//          R5 quad-split+no-NT 298.9 (confounded: no-NT pass1); R6 f4loads
//          296.6; R7 f4loads+LDS 295.6 (R6~=R7 => 4px/thread pass-1 was the
//          regression, stores neutral); R8 12B records 287.7 (best).
//          R9(this) = R8 pass1 + quad-split pass2 (isolates R5's confound).
// dur_us carries ~185us of in-stream harness restore/poison overhead
// (768MiB ws poison fill ~121us + input restore).

#define NSAMP   131072
#define HI_W    2048
#define LO_W    512
#define HI_PIX  (HI_W * HI_W)            // 4,194,304
#define LO_PIX  (LO_W * LO_W)            // 262,144
#define HI_PX_BLOCKS (HI_PIX / 256)      // 16384  (1 px/thread)
#define LO_PX_BLOCKS (LO_PIX / 256)      // 1024
#define WS_NEED ((size_t)HI_PIX * 12 + (size_t)LO_PIX * 4)   // 49 MiB

typedef float fx4 __attribute__((ext_vector_type(4)));   // NT-store-compatible

__device__ __forceinline__ unsigned int quant_u(float v, float qmax) {
    return (unsigned int)rintf(fminf(fmaxf(v, 0.0f), 1.0f) * qmax);
}

// ---- Pass 1: quantize + transpose to channel-last u8, 1 px/thread ----------
__global__ __launch_bounds__(256)
void quant_pack_kernel(const float* __restrict__ hi,     // [12][HI_PIX]
                       const float* __restrict__ lo,     // [4][LO_PIX]
                       unsigned int* __restrict__ hiT,   // [HI_PIX*3] dwords
                       unsigned int* __restrict__ loT)   // [LO_PIX]
{
    __shared__ unsigned int lds[768];                    // 3 KiB: 256 px * 12B
    const int t = threadIdx.x;
    const int b = blockIdx.x;
    if (b < HI_PX_BLOCKS) {
        const int p = b * 256 + t;
        unsigned int w0 = 0, w1 = 0, w2 = 0;
        #pragma unroll
        for (int c = 0; c < 4; ++c)
            w0 |= quant_u(__builtin_nontemporal_load(hi + (size_t)c * HI_PIX + p), 255.0f) << (c * 8);
        #pragma unroll
        for (int c = 4; c < 8; ++c)
            w1 |= quant_u(__builtin_nontemporal_load(hi + (size_t)c * HI_PIX + p), 255.0f) << ((c - 4) * 8);
        #pragma unroll
        for (int c = 8; c < 12; ++c)
            w2 |= quant_u(__builtin_nontemporal_load(hi + (size_t)c * HI_PIX + p), 255.0f) << ((c - 8) * 8);
        // 12B/px into LDS; addr stride 3 dwords, gcd(3,32)=1 -> conflict-free
        lds[3 * t + 0] = w0;
        lds[3 * t + 1] = w1;
        lds[3 * t + 2] = w2;
        __syncthreads();
        // waves 0-2 store the block's 3072B contiguously, 16B/lane dense;
        // wave 3 idles (no intra-wave divergence)
        if (t < 192) {
            const uint4 v = *(const uint4*)&lds[4 * t];  // dense ds_read_b128
            *((uint4*)(hiT + (size_t)b * 768) + t) = v;  // 16B/lane, coalesced
        }
    } else {
        const int p = (b - HI_PX_BLOCKS) * 256 + t;
        unsigned int w = 0;
        #pragma unroll
        for (int c = 0; c < 4; ++c)
            w |= quant_u(__builtin_nontemporal_load(lo + (size_t)c * LO_PIX + p), 15.0f) << (c * 8);
        loT[p] = w;                                      // 4B/lane dense
    }
}

// ---- Pass 2: bilinear sample, 4 lanes per sample (lane = corner) -----------
__global__ __launch_bounds__(256)
void sample_kernel(const float2* __restrict__ uv,
                   const unsigned int* __restrict__ hiT,  // 12B/px records
                   const unsigned int* __restrict__ loT,
                   fx4* __restrict__ out)
{
    const int tid = blockIdx.x * 256 + threadIdx.x;
    const int s  = tid >> 2;       // sample
    const int l  = tid & 3;        // corner lane
    const int xt = l & 1;          // x-tap
    const int yt = l >> 1;         // y-tap

    const float2 p = uv[s];        // quad-broadcast

    // ---------- hi coords (2048x2048) ----------
    const float gxh = p.x * 2.0f - 1.0f, gyh = p.y * 2.0f - 1.0f;
    const float ixh = (gxh + 1.0f) * 0.5f * (float)(HI_W - 1);
    const float iyh = (gyh + 1.0f) * 0.5f * (float)(HI_W - 1);
    const float ixh0f = floorf(ixh), iyh0f = floorf(iyh);
    const float wxh = ixh - ixh0f, wyh = iyh - iyh0f;
    int ixh0 = min(max((int)ixh0f, 0), HI_W - 1);
    int iyh0 = min(max((int)iyh0f, 0), HI_W - 1);
    const int xh = xt ? min(ixh0 + 1, HI_W - 1) : ixh0;
    const int yh = yt ? min(iyh0 + 1, HI_W - 1) : iyh0;
    const float wgt_h = (xt ? wxh : 1.0f - wxh) * (yt ? wyh : 1.0f - wyh);

    // ---------- lo coords (512x512) ----------
    const float ixl = (gxh + 1.0f) * 0.5f * (float)(LO_W - 1);
    const float iyl = (gyh + 1.0f) * 0.5f * (float)(LO_W - 1);
    const float ixl0f = floorf(ixl), iyl0f = floorf(iyl);
    const float wxl = ixl - ixl0f, wyl = iyl - iyl0f;
    int ixl0 = min(max((int)ixl0f, 0), LO_W - 1);
    int iyl0 = min(max((int)iyl0f, 0), LO_W - 1);
    const int xl = xt ? min(ixl0 + 1, LO_W - 1) : ixl0;
    const int yl = yt ? min(iyl0 + 1, LO_W - 1) : iyl0;
    const float wgt_l = (xt ? wxl : 1.0f - wxl) * (yt ? wyl : 1.0f - wyl);

    // one 12B hi texel + one lo dword per lane (x-pair lanes line-adjacent)
    const unsigned int* h = hiT + 3 * ((size_t)yh * HI_W + xh);
    unsigned int u[3];
    u[0] = h[0]; u[1] = h[1]; u[2] = h[2];               // dwordx3
    const unsigned int lw = loT[yl * LO_W + xl];

    float r[16];
    #pragma unroll
    for (int c = 0; c < 12; ++c)
        r[c] = wgt_h * (float)((u[c >> 2] >> ((c & 3) * 8)) & 0xff);
    #pragma unroll
    for (int c = 0; c < 4; ++c)
        r[12 + c] = wgt_l * (float)((lw >> (c * 8)) & 0xff);

    // 2-step butterfly: sum the 4 corner contributions across the lane quad
    #pragma unroll
    for (int j = 0; j < 16; ++j) {
        r[j] += __shfl_xor(r[j], 1);
        r[j] += __shfl_xor(r[j], 2);
    }

    // lane l stores channels [4l, 4l+4): one fx4 -> wave = 1KB dense
    fx4 v;
    #pragma unroll
    for (int j = 0; j < 4; ++j) {
        const int c = 4 * l + j;
        v[j] = r[c] * ((c < 12) ? (1.0f / 255.0f) : (1.0f / 15.0f));
    }
    __builtin_nontemporal_store(v, &out[tid]);
}

// ---- Fallback (round-1 direct kernel) if ws is unexpectedly small ----------
__global__ __launch_bounds__(256)
void direct_kernel(const float2* __restrict__ uv,
                   const float*  __restrict__ hi,
                   const float*  __restrict__ lo,
                   float*        __restrict__ out)
{
    const int tid = blockIdx.x * 256 + threadIdx.x;
    const int s = tid >> 4, c = tid & 15;
    const float2 p = uv[s];
    const float* tex; int W; float qmax, rq;
    if (c < 12) { tex = hi + (size_t)c * HI_PIX; W = HI_W; qmax = 255.0f; rq = 1.0f/255.0f; }
    else        { tex = lo + (size_t)(c-12) * LO_PIX; W = LO_W; qmax = 15.0f; rq = 1.0f/15.0f; }
    const float gx = p.x * 2.0f - 1.0f, gy = p.y * 2.0f - 1.0f;
    const float ix = (gx + 1.0f) * 0.5f * (float)(W - 1);
    const float iy = (gy + 1.0f) * 0.5f * (float)(W - 1);
    const float ix0f = floorf(ix), iy0f = floorf(iy);
    const float wx = ix - ix0f, wy = iy - iy0f;
    int ix0 = min(max((int)ix0f, 0), W - 1);
    int iy0 = min(max((int)iy0f, 0), W - 1);
    const int ix1 = min(ix0 + 1, W - 1), iy1 = min(iy0 + 1, W - 1);
    const float* r0 = tex + (size_t)iy0 * W;
    const float* r1 = tex + (size_t)iy1 * W;
    float v00 = rintf(fminf(fmaxf(r0[ix0],0.f),1.f)*qmax)*rq;
    float v01 = rintf(fminf(fmaxf(r0[ix1],0.f),1.f)*qmax)*rq;
    float v10 = rintf(fminf(fmaxf(r1[ix0],0.f),1.f)*qmax)*rq;
    float v11 = rintf(fminf(fmaxf(r1[ix1],0.f),1.f)*qmax)*rq;
    out[(size_t)s*16 + c] = v00*(1.f-wy)*(1.f-wx) + v01*(1.f-wy)*wx
                          + v10*wy*(1.f-wx)       + v11*wy*wx;
}

extern "C" void kernel_launch(void* const* d_in, const int* in_sizes, int n_in,
                              void* d_out, int out_size, void* d_ws, size_t ws_size,
                              hipStream_t stream) {
    const float2* uv = (const float2*)d_in[0];
    const float*  hi = (const float*)d_in[1];
    const float*  lo = (const float*)d_in[2];
    float* out = (float*)d_out;

    if (ws_size < WS_NEED) {
        direct_kernel<<<(NSAMP * 16) / 256, 256, 0, stream>>>(uv, hi, lo, out);
        return;
    }

    unsigned int* hiT = (unsigned int*)d_ws;                                 // 48 MiB
    unsigned int* loT = (unsigned int*)((char*)d_ws + (size_t)HI_PIX * 12);  // 1 MiB

    quant_pack_kernel<<<HI_PX_BLOCKS + LO_PX_BLOCKS, 256, 0, stream>>>(hi, lo, hiT, loT);
    sample_kernel<<<(NSAMP * 4) / 256, 256, 0, stream>>>(uv, hiT, loT, (fx4*)out);
}

// Round 5
// 284.740 us; speedup vs baseline: 1.0130x; 1.0130x over previous
//
#include <hip/hip_runtime.h>

// LatentTexture: quantize-STE (8b hi / 4b lo) + align_corners bilinear sample.
// Two-pass through d_ws:
//   pass 1: streaming quantize + channel-last u8 repack, 1 px/thread scalar
//           NT loads (dense 256B/wave runs), 12B/px hiT records in
//           ROW-PAIR-INTERLEAVED order: R(x,y) = (y>>1)*2W + 2x + (y&1).
//           Block covers 128x*2y patch; LDS repack lds[3*(2p+r)+j]
//           (stride 6 -> 2-way bank alias = free), threads 0..191 store the
//           block's 3072B contiguously, 16B/lane dense (same as R8).
//   pass 2: 4 lanes/sample (lane = corner). With pair-interleave, the 4 hi
//           records of a quad are 48B CONTIGUOUS when y0 is even (prob 1/2)
//           -> E[lines/sample] ~2.2 vs 2.75 flat: ~20% less L3 line traffic
//           on the dominant texture. Butterfly sum + 1KB-dense fx4 stores.
// History: R1 direct 311; R2 308.6; R4 1px+NT+uint4 292.4/290.2; R5 298.9;
//          R6 296.6 ~= R7 295.6 (4px/thread pass-1 was the regression);
//          R8 12B records 287.7 (best; delta = write-bytes at 6.4TB/s =>
//          pass-1 BW-bound); R9 quad-split 288.4 (occupancy-neutral =>
//          pass-2 not latency-bound). R10(this) = pair-interleaved hiT
//          (attacks pass-2 line count, the last unminimized term).
// dur_us carries large fixed in-stream harness overhead (768MiB ws poison
// fill ~121us + restores); controllable kernel portion ~60-100us.

#define NSAMP   131072
#define HI_W    2048
#define LO_W    512
#define HI_PIX  (HI_W * HI_W)            // 4,194,304
#define LO_PIX  (LO_W * LO_W)            // 262,144
#define HI_PX_BLOCKS (HI_PIX / 256)      // 16384  (256 px/block: 128x * 2y)
#define LO_PX_BLOCKS (LO_PIX / 256)      // 1024
#define WS_NEED ((size_t)HI_PIX * 12 + (size_t)LO_PIX * 4)   // 49 MiB

typedef float fx4 __attribute__((ext_vector_type(4)));   // NT-store-compatible

__device__ __forceinline__ unsigned int quant_u(float v, float qmax) {
    return (unsigned int)rintf(fminf(fmaxf(v, 0.0f), 1.0f) * qmax);
}

// ---- Pass 1: quantize + repack to pair-interleaved channel-last u8 ---------
__global__ __launch_bounds__(256)
void quant_pack_kernel(const float* __restrict__ hi,     // [12][HI_PIX]
                       const float* __restrict__ lo,     // [4][LO_PIX]
                       unsigned int* __restrict__ hiT,   // [HI_PIX*3] dwords
                       unsigned int* __restrict__ loT)   // [LO_PIX]
{
    __shared__ unsigned int lds[768];                    // 3 KiB: 256 px * 12B
    const int t = threadIdx.x;
    const int b = blockIdx.x;
    if (b < HI_PX_BLOCKS) {
        // block covers x0..x0+127, rows y0..y0+1  (16 blocks per pair-row)
        const int P  = b >> 4;                 // pair-row index [0,1024)
        const int x0 = (b & 15) << 7;          // 128-px x tile
        const int r  = t >> 7;                 // row within pair (0/1)
        const int p  = t & 127;                // x within tile
        const size_t pix = (size_t)(2 * P + r) * HI_W + x0 + p;
        unsigned int w0 = 0, w1 = 0, w2 = 0;
        #pragma unroll
        for (int c = 0; c < 4; ++c)
            w0 |= quant_u(__builtin_nontemporal_load(hi + (size_t)c * HI_PIX + pix), 255.0f) << (c * 8);
        #pragma unroll
        for (int c = 4; c < 8; ++c)
            w1 |= quant_u(__builtin_nontemporal_load(hi + (size_t)c * HI_PIX + pix), 255.0f) << ((c - 4) * 8);
        #pragma unroll
        for (int c = 8; c < 12; ++c)
            w2 |= quant_u(__builtin_nontemporal_load(hi + (size_t)c * HI_PIX + pix), 255.0f) << ((c - 8) * 8);
        // local record = 2p + r; dword addr stride 6 -> 2-way bank alias (free)
        const int lr = 2 * p + r;
        lds[3 * lr + 0] = w0;
        lds[3 * lr + 1] = w1;
        lds[3 * lr + 2] = w2;
        __syncthreads();
        // block's records are contiguous: base R = P*4096 + 2*x0
        if (t < 192) {
            const uint4 v = *(const uint4*)&lds[4 * t];  // dense ds_read_b128
            *((uint4*)(hiT + 3 * ((size_t)P * 2 * HI_W + 2 * x0)) + t) = v;
        }
    } else {
        const int pl = (b - HI_PX_BLOCKS) * 256 + t;
        unsigned int w = 0;
        #pragma unroll
        for (int c = 0; c < 4; ++c)
            w |= quant_u(__builtin_nontemporal_load(lo + (size_t)c * LO_PIX + pl), 15.0f) << (c * 8);
        loT[pl] = w;                                     // 4B/lane dense
    }
}

// ---- Pass 2: bilinear sample, 4 lanes per sample (lane = corner) -----------
__global__ __launch_bounds__(256)
void sample_kernel(const float2* __restrict__ uv,
                   const unsigned int* __restrict__ hiT,  // pair-interleaved
                   const unsigned int* __restrict__ loT,
                   fx4* __restrict__ out)
{
    const int tid = blockIdx.x * 256 + threadIdx.x;
    const int s  = tid >> 2;       // sample
    const int l  = tid & 3;        // corner lane
    const int xt = l & 1;          // x-tap
    const int yt = l >> 1;         // y-tap

    const float2 p = uv[s];        // quad-broadcast

    // ---------- hi coords (2048x2048) ----------
    const float gxh = p.x * 2.0f - 1.0f, gyh = p.y * 2.0f - 1.0f;
    const float ixh = (gxh + 1.0f) * 0.5f * (float)(HI_W - 1);
    const float iyh = (gyh + 1.0f) * 0.5f * (float)(HI_W - 1);
    const float ixh0f = floorf(ixh), iyh0f = floorf(iyh);
    const float wxh = ixh - ixh0f, wyh = iyh - iyh0f;
    int ixh0 = min(max((int)ixh0f, 0), HI_W - 1);
    int iyh0 = min(max((int)iyh0f, 0), HI_W - 1);
    const int xh = xt ? min(ixh0 + 1, HI_W - 1) : ixh0;
    const int yh = yt ? min(iyh0 + 1, HI_W - 1) : iyh0;
    const float wgt_h = (xt ? wxh : 1.0f - wxh) * (yt ? wyh : 1.0f - wyh);

    // ---------- lo coords (512x512) ----------
    const float ixl = (gxh + 1.0f) * 0.5f * (float)(LO_W - 1);
    const float iyl = (gyh + 1.0f) * 0.5f * (float)(LO_W - 1);
    const float ixl0f = floorf(ixl), iyl0f = floorf(iyl);
    const float wxl = ixl - ixl0f, wyl = iyl - iyl0f;
    int ixl0 = min(max((int)ixl0f, 0), LO_W - 1);
    int iyl0 = min(max((int)iyl0f, 0), LO_W - 1);
    const int xl = xt ? min(ixl0 + 1, LO_W - 1) : ixl0;
    const int yl = yt ? min(iyl0 + 1, LO_W - 1) : iyl0;
    const float wgt_l = (xt ? wxl : 1.0f - wxl) * (yt ? wyl : 1.0f - wyl);

    // one 12B hi texel per lane; pair-interleaved record index:
    // quad records are 48B contiguous when yh0 is even (prob 1/2)
    const size_t R = (size_t)(yh >> 1) * (2 * HI_W) + 2 * xh + (yh & 1);
    const unsigned int* h = hiT + 3 * R;
    unsigned int u[3];
    u[0] = h[0]; u[1] = h[1]; u[2] = h[2];               // dwordx3
    const unsigned int lw = loT[yl * LO_W + xl];

    float r[16];
    #pragma unroll
    for (int c = 0; c < 12; ++c)
        r[c] = wgt_h * (float)((u[c >> 2] >> ((c & 3) * 8)) & 0xff);
    #pragma unroll
    for (int c = 0; c < 4; ++c)
        r[12 + c] = wgt_l * (float)((lw >> (c * 8)) & 0xff);

    // 2-step butterfly: sum the 4 corner contributions across the lane quad
    #pragma unroll
    for (int j = 0; j < 16; ++j) {
        r[j] += __shfl_xor(r[j], 1);
        r[j] += __shfl_xor(r[j], 2);
    }

    // lane l stores channels [4l, 4l+4): one fx4 -> wave = 1KB dense
    fx4 v;
    #pragma unroll
    for (int j = 0; j < 4; ++j) {
        const int c = 4 * l + j;
        v[j] = r[c] * ((c < 12) ? (1.0f / 255.0f) : (1.0f / 15.0f));
    }
    __builtin_nontemporal_store(v, &out[tid]);
}

// ---- Fallback (round-1 direct kernel) if ws is unexpectedly small ----------
__global__ __launch_bounds__(256)
void direct_kernel(const float2* __restrict__ uv,
                   const float*  __restrict__ hi,
                   const float*  __restrict__ lo,
                   float*        __restrict__ out)
{
    const int tid = blockIdx.x * 256 + threadIdx.x;
    const int s = tid >> 4, c = tid & 15;
    const float2 p = uv[s];
    const float* tex; int W; float qmax, rq;
    if (c < 12) { tex = hi + (size_t)c * HI_PIX; W = HI_W; qmax = 255.0f; rq = 1.0f/255.0f; }
    else        { tex = lo + (size_t)(c-12) * LO_PIX; W = LO_W; qmax = 15.0f; rq = 1.0f/15.0f; }
    const float gx = p.x * 2.0f - 1.0f, gy = p.y * 2.0f - 1.0f;
    const float ix = (gx + 1.0f) * 0.5f * (float)(W - 1);
    const float iy = (gy + 1.0f) * 0.5f * (float)(W - 1);
    const float ix0f = floorf(ix), iy0f = floorf(iy);
    const float wx = ix - ix0f, wy = iy - iy0f;
    int ix0 = min(max((int)ix0f, 0), W - 1);
    int iy0 = min(max((int)iy0f, 0), W - 1);
    const int ix1 = min(ix0 + 1, W - 1), iy1 = min(iy0 + 1, W - 1);
    const float* r0 = tex + (size_t)iy0 * W;
    const float* r1 = tex + (size_t)iy1 * W;
    float v00 = rintf(fminf(fmaxf(r0[ix0],0.f),1.f)*qmax)*rq;
    float v01 = rintf(fminf(fmaxf(r0[ix1],0.f),1.f)*qmax)*rq;
    float v10 = rintf(fminf(fmaxf(r1[ix0],0.f),1.f)*qmax)*rq;
    float v11 = rintf(fminf(fmaxf(r1[ix1],0.f),1.f)*qmax)*rq;
    out[(size_t)s*16 + c] = v00*(1.f-wy)*(1.f-wx) + v01*(1.f-wy)*wx
                          + v10*wy*(1.f-wx)       + v11*wy*wx;
}

extern "C" void kernel_launch(void* const* d_in, const int* in_sizes, int n_in,
                              void* d_out, int out_size, void* d_ws, size_t ws_size,
                              hipStream_t stream) {
    const float2* uv = (const float2*)d_in[0];
    const float*  hi = (const float*)d_in[1];
    const float*  lo = (const float*)d_in[2];
    float* out = (float*)d_out;

    if (ws_size < WS_NEED) {
        direct_kernel<<<(NSAMP * 16) / 256, 256, 0, stream>>>(uv, hi, lo, out);
        return;
    }

    unsigned int* hiT = (unsigned int*)d_ws;                                 // 48 MiB
    unsigned int* loT = (unsigned int*)((char*)d_ws + (size_t)HI_PIX * 12);  // 1 MiB

    quant_pack_kernel<<<HI_PX_BLOCKS + LO_PX_BLOCKS, 256, 0, stream>>>(hi, lo, hiT, loT);
    sample_kernel<<<(NSAMP * 4) / 256, 256, 0, stream>>>(uv, hiT, loT, (fx4*)out);
}